// Round 1
// baseline (627.638 us; speedup 1.0000x reference)
//
#include <hip/hip_runtime.h>
#include <stdint.h>

// Problem constants
#define BD   16
#define CD   512
#define HD_  64
#define NH_  8
#define HWD  4096
#define LD   77
#define DD   768

typedef __bf16 bf16;
typedef bf16 bf16x8 __attribute__((ext_vector_type(8)));
typedef float f32x4 __attribute__((ext_vector_type(4)));

__device__ __forceinline__ void async16(const bf16* g, bf16* l) {
  __builtin_amdgcn_global_load_lds(
      (const __attribute__((address_space(1))) void*)g,
      (__attribute__((address_space(3))) void*)l, 16, 0, 0);
}

__device__ __forceinline__ unsigned short bfb(float f) {
  bf16 h = (bf16)f;
  return __builtin_bit_cast(unsigned short, h);
}

// ---------------------------------------------------------------------------
// K0a: transpose+convert x [B,C,HW] f32 -> xt [B*HW, C] bf16 (LDS tile xpose)
// ---------------------------------------------------------------------------
__global__ __launch_bounds__(256) void xpose_cvt(const float* __restrict__ X,
                                                 bf16* __restrict__ Y) {
  __shared__ float tile[64][68];
  const int b = blockIdx.z, c0 = blockIdx.y * 64, t0 = blockIdx.x * 64;
  const int tid = threadIdx.x;
  const float* Xb = X + ((size_t)b * CD + c0) * HWD + t0;
#pragma unroll
  for (int p = 0; p < 4; ++p) {
    int c = (tid >> 4) + p * 16;
    int t = (tid & 15) * 4;
    float4 v = *(const float4*)(Xb + (size_t)c * HWD + t);
    *(float4*)&tile[c][t] = v;
  }
  __syncthreads();
  int t = tid >> 2, cb = (tid & 3) * 16;
  union { uint4 u[2]; unsigned short us[16]; } pk;
#pragma unroll
  for (int j = 0; j < 16; ++j) pk.us[j] = bfb(tile[cb + j][t]);
  uint4* Yp = (uint4*)(Y + ((size_t)(b * HWD + t0 + t)) * CD + c0 + cb);
  Yp[0] = pk.u[0];
  Yp[1] = pk.u[1];
}

// ---------------------------------------------------------------------------
// K0b: generic f32 -> bf16 convert (n multiple of 8)
// ---------------------------------------------------------------------------
__global__ void cvt_bf16_k(const float* __restrict__ X, bf16* __restrict__ Y, int n) {
  int i = (blockIdx.x * 256 + threadIdx.x) * 8;
  if (i >= n) return;
  float4 a = *(const float4*)(X + i);
  float4 c = *(const float4*)(X + i + 4);
  union { uint4 u; unsigned short us[8]; } pk;
  pk.us[0] = bfb(a.x); pk.us[1] = bfb(a.y); pk.us[2] = bfb(a.z); pk.us[3] = bfb(a.w);
  pk.us[4] = bfb(c.x); pk.us[5] = bfb(c.y); pk.us[6] = bfb(c.z); pk.us[7] = bfb(c.w);
  *(uint4*)(Y + i) = pk.u;
}

// ---------------------------------------------------------------------------
// m97-style GEMM: D[M,N] = A[M,K] * B[N,K]^T (+ mode-specific epilogue)
// MODE 0: Q-proj  -> D fp32 [M,512], += bq[n] + 0.05*pe(n, token m)
// MODE 1: K/V-proj-> D fp32 [M,512], += bias[n], rows guarded by M
// MODE 3: O-proj  -> m = out-channel, n = token; D = out[B,C,HW] fp32,
//                    += bo[m] + x[b,m,hw] residual
// ---------------------------------------------------------------------------
template <int TM, int TN, int MODE>
__global__ __launch_bounds__(256)
void gemm_bt(const bf16* __restrict__ A, const bf16* __restrict__ B,
             int M, int N, int K,
             const float* __restrict__ bias, const float* __restrict__ xres,
             float* __restrict__ D) {
  constexpr int WM = TM / 2, WN = TN / 2;
  constexpr int AFR = WM / 16, BFR = WN / 16;
  constexpr int ACH = TM / 8, TCH = (TM + TN) / 8, WCH = TCH / 4;
  __shared__ bf16 sA[TM * 64];
  __shared__ bf16 sB[TN * 64];
  const int tid = threadIdx.x, wave = tid >> 6, lane = tid & 63;
  const int m0 = blockIdx.y * TM, n0 = blockIdx.x * TN;
  const int wm = (wave >> 1) * WM, wn = (wave & 1) * WN;
  const int sub = lane >> 3, col8 = (lane & 7) * 8;
  const int mlo = lane & 15, khi = lane >> 4;
  f32x4 acc[AFR][BFR] = {};

  for (int k0 = 0; k0 < K; k0 += 64) {
#pragma unroll
    for (int r = 0; r < WCH; ++r) {
      int ci = wave * WCH + r;
      if (ci < ACH) {
        int row = ci * 8 + sub;
        int g = m0 + row;
        if (g > M - 1) g = M - 1;  // clamp partial M-tiles (KV GEMM)
        async16(A + (size_t)g * K + k0 + col8, &sA[ci * 512]);
      } else {
        int cj = ci - ACH;
        int row = cj * 8 + sub;
        async16(B + (size_t)(n0 + row) * K + k0 + col8, &sB[cj * 512]);
      }
    }
    __syncthreads();
#pragma unroll
    for (int kc = 0; kc < 2; ++kc) {
      bf16x8 af[AFR], bfv[BFR];
      const int ko = kc * 32 + khi * 8;
#pragma unroll
      for (int i = 0; i < AFR; ++i)
        af[i] = *(const bf16x8*)&sA[(wm + i * 16 + mlo) * 64 + ko];
#pragma unroll
      for (int j = 0; j < BFR; ++j)
        bfv[j] = *(const bf16x8*)&sB[(wn + j * 16 + mlo) * 64 + ko];
#pragma unroll
      for (int i = 0; i < AFR; ++i)
#pragma unroll
        for (int j = 0; j < BFR; ++j)
          acc[i][j] = __builtin_amdgcn_mfma_f32_16x16x32_bf16(af[i], bfv[j],
                                                              acc[i][j], 0, 0, 0);
    }
    __syncthreads();
  }

#pragma unroll
  for (int i = 0; i < AFR; ++i) {
    const int mb = m0 + wm + i * 16 + khi * 4;
#pragma unroll
    for (int j = 0; j < BFR; ++j) {
      const int n = n0 + wn + j * 16 + mlo;
#pragma unroll
      for (int r = 0; r < 4; ++r) {
        const int m = mb + r;
        float val = acc[i][j][r];
        if constexpr (MODE == 0) {
          int hw = m & (HWD - 1);
          float pe = (n < 256) ? (float)(hw & 63) : (float)(hw >> 6);
          val += bias[n] + (0.05f / 63.0f) * pe;
          D[(size_t)m * CD + n] = val;
        } else if constexpr (MODE == 1) {
          if (m < M) D[(size_t)m * CD + n] = val + bias[n];
        } else {
          int b = n >> 12, hw = n & (HWD - 1);
          size_t addr = ((size_t)(b * CD + m)) * HWD + hw;
          D[addr] = val + bias[m] + xres[addr];
        }
      }
    }
  }
}

// ---------------------------------------------------------------------------
// LayerNorm over rows of 512 (wave per row).
// khlayout=0: Y row-major [rows,512] bf16 (q path)
// khlayout=1: Y = kh [B,NH,L,HD] bf16 (k path, head-split)
// ---------------------------------------------------------------------------
__global__ __launch_bounds__(256) void ln_rows(const float* __restrict__ X,
                                               const float* __restrict__ gg,
                                               const float* __restrict__ bb,
                                               bf16* __restrict__ Y, int nrows,
                                               int khlayout) {
  const int wv = threadIdx.x >> 6, lane = threadIdx.x & 63;
  const int row = blockIdx.x * 4 + wv;
  if (row >= nrows) return;
  const float* xr = X + (size_t)row * CD + lane * 8;
  float4 v0 = *(const float4*)xr;
  float4 v1 = *(const float4*)(xr + 4);
  float xv[8] = {v0.x, v0.y, v0.z, v0.w, v1.x, v1.y, v1.z, v1.w};
  float s = 0.f, sq = 0.f;
#pragma unroll
  for (int j = 0; j < 8; ++j) { s += xv[j]; sq += xv[j] * xv[j]; }
#pragma unroll
  for (int off = 1; off < 64; off <<= 1) {
    s += __shfl_xor(s, off);
    sq += __shfl_xor(sq, off);
  }
  float mean = s * (1.0f / 512.0f);
  float var = sq * (1.0f / 512.0f) - mean * mean;
  float rstd = rsqrtf(var + 1e-5f);
  const int c0 = lane * 8;
  union { uint4 u; unsigned short us[8]; } pk;
#pragma unroll
  for (int j = 0; j < 8; ++j)
    pk.us[j] = bfb((xv[j] - mean) * rstd * gg[c0 + j] + bb[c0 + j]);
  size_t ya;
  if (khlayout) {
    int bq = row / LD, l = row - bq * LD;
    int hh = lane >> 3, dd = (lane & 7) * 8;
    ya = (((size_t)(bq * NH_ + hh)) * LD + l) * HD_ + dd;
  } else {
    ya = (size_t)row * CD + c0;
  }
  *(uint4*)(Y + ya) = pk.u;
}

// ---------------------------------------------------------------------------
// vraw [B*L, 512] fp32 -> vt [B*NH, HD, 96] bf16 (key dim transposed,
// cols 77..95 zero so PV K-loop can run over 96 with no masking)
// ---------------------------------------------------------------------------
__global__ __launch_bounds__(256) void make_vt(const float* __restrict__ vraw,
                                               bf16* __restrict__ vt) {
  const int bh = blockIdx.x, b = bh >> 3, h = bh & 7;
  const int tid = threadIdx.x, d = tid & 63, lg = tid >> 6;
  for (int l = lg; l < 96; l += 4) {
    float v = 0.f;
    if (l < LD) v = vraw[((size_t)(b * LD + l)) * CD + h * HD_ + d];
    vt[((size_t)(bh * HD_ + d)) * 96 + l] = (bf16)v;
  }
}

// ---------------------------------------------------------------------------
// Attention: block = (64 queries, head h, batch b); 4 waves x 16-query strips.
// S = Q K^T (MFMA), in-register softmax over 77 keys, P through LDS
// (C-layout -> A-layout), O = P V (MFMA, V pre-transposed & zero-padded).
// ---------------------------------------------------------------------------
__global__ __launch_bounds__(256) void attn_k(const bf16* __restrict__ Q,
                                              const bf16* __restrict__ KH,
                                              const bf16* __restrict__ VT,
                                              bf16* __restrict__ O) {
  __shared__ bf16 P[4][16 * 104];  // per-wave 16x96 P, stride 104 vs bank conflicts
  const int tid = threadIdx.x, wv = tid >> 6, lane = tid & 63;
  const int m = lane & 15, kg = lane >> 4;
  const int q0 = blockIdx.x * 64, h = blockIdx.y, b = blockIdx.z;
  const int bh = b * NH_ + h;

  // Q A-frags straight from global (read-once data)
  const size_t qoff = ((size_t)(b * HWD + q0 + wv * 16 + m)) * CD + h * HD_;
  bf16x8 a0 = *(const bf16x8*)(Q + qoff + kg * 8);
  bf16x8 a1 = *(const bf16x8*)(Q + qoff + 32 + kg * 8);

  // S = Q K^T : 5 key tiles of 16
  const bf16* Kb = KH + (size_t)bh * LD * HD_;
  f32x4 s[5];
#pragma unroll
  for (int kt = 0; kt < 5; ++kt) {
    int key = kt * 16 + m;
    if (key > LD - 1) key = LD - 1;  // clamped rows get masked below
    const bf16* kr = Kb + key * HD_ + kg * 8;
    bf16x8 b0 = *(const bf16x8*)kr;
    bf16x8 b1 = *(const bf16x8*)(kr + 32);
    f32x4 z = {0.f, 0.f, 0.f, 0.f};
    z = __builtin_amdgcn_mfma_f32_16x16x32_bf16(a0, b0, z, 0, 0, 0);
    z = __builtin_amdgcn_mfma_f32_16x16x32_bf16(a1, b1, z, 0, 0, 0);
    s[kt] = z;
  }

  // softmax per row (row = kg*4+r, cols live in lanes kg*16..kg*16+15)
  bf16* Pw = &P[wv][0];
#pragma unroll
  for (int r = 0; r < 4; ++r) {
    float sc[5];
#pragma unroll
    for (int kt = 0; kt < 5; ++kt) {
      float v = s[kt][r] * 0.125f;  // HD^-0.5
      if (kt == 4 && m >= LD - 64) v = -3.0e38f;
      sc[kt] = v;
    }
    float mx = fmaxf(fmaxf(fmaxf(sc[0], sc[1]), fmaxf(sc[2], sc[3])), sc[4]);
    mx = fmaxf(mx, __shfl_xor(mx, 1));
    mx = fmaxf(mx, __shfl_xor(mx, 2));
    mx = fmaxf(mx, __shfl_xor(mx, 4));
    mx = fmaxf(mx, __shfl_xor(mx, 8));
    float sum = 0.f;
#pragma unroll
    for (int kt = 0; kt < 5; ++kt) {
      sc[kt] = __expf(sc[kt] - mx);
      sum += sc[kt];
    }
    sum += __shfl_xor(sum, 1);
    sum += __shfl_xor(sum, 2);
    sum += __shfl_xor(sum, 4);
    sum += __shfl_xor(sum, 8);
    float inv = 1.0f / sum;
    const int prow = kg * 4 + r;
#pragma unroll
    for (int kt = 0; kt < 5; ++kt)
      Pw[prow * 104 + kt * 16 + m] = (bf16)(sc[kt] * inv);
    Pw[prow * 104 + 80 + m] = (bf16)0.f;  // zero pad cols 80..95
  }
  __syncthreads();

  // O = P V : A-frags from LDS P, B-frags from global vt (L2-resident)
  bf16x8 ap[3];
#pragma unroll
  for (int kc = 0; kc < 3; ++kc)
    ap[kc] = *(const bf16x8*)&Pw[m * 104 + kc * 32 + kg * 8];

  const bf16* Vb = VT + (size_t)bh * HD_ * 96;
  f32x4 o[4] = {};
#pragma unroll
  for (int nt = 0; nt < 4; ++nt) {
#pragma unroll
    for (int kc = 0; kc < 3; ++kc) {
      bf16x8 bv = *(const bf16x8*)(Vb + (nt * 16 + m) * 96 + kc * 32 + kg * 8);
      o[nt] = __builtin_amdgcn_mfma_f32_16x16x32_bf16(ap[kc], bv, o[nt], 0, 0, 0);
    }
  }
#pragma unroll
  for (int nt = 0; nt < 4; ++nt)
#pragma unroll
    for (int r = 0; r < 4; ++r) {
      const int row = b * HWD + q0 + wv * 16 + kg * 4 + r;
      O[(size_t)row * CD + h * HD_ + nt * 16 + m] = (bf16)(o[nt][r]);
    }
}

// ---------------------------------------------------------------------------
extern "C" void kernel_launch(void* const* d_in, const int* in_sizes, int n_in,
                              void* d_out, int out_size, void* d_ws, size_t ws_size,
                              hipStream_t stream) {
  const float* x    = (const float*)d_in[0];
  const float* text = (const float*)d_in[1];
  const float* wq   = (const float*)d_in[2];
  const float* bq   = (const float*)d_in[3];
  const float* wk   = (const float*)d_in[4];
  const float* bk   = (const float*)d_in[5];
  const float* wv   = (const float*)d_in[6];
  const float* bv   = (const float*)d_in[7];
  const float* wo   = (const float*)d_in[8];
  const float* bo   = (const float*)d_in[9];
  const float* g1   = (const float*)d_in[10];
  const float* b1   = (const float*)d_in[11];
  const float* g2   = (const float*)d_in[12];
  const float* b2   = (const float*)d_in[13];
  float* out = (float*)d_out;

  char* p = (char*)d_ws;
  auto alloc = [&](size_t bytes) {
    char* r = p;
    p += (bytes + 255) & ~(size_t)255;
    return r;
  };
  bf16* xt     = (bf16*)alloc((size_t)BD * HWD * CD * 2);  // reused as qbf later
  bf16* attn_o = (bf16*)alloc((size_t)BD * HWD * CD * 2);
  bf16* textb  = (bf16*)alloc((size_t)BD * LD * DD * 2);
  bf16* wqb    = (bf16*)alloc((size_t)CD * CD * 2);
  bf16* wkb    = (bf16*)alloc((size_t)CD * DD * 2);
  bf16* wvb    = (bf16*)alloc((size_t)CD * DD * 2);
  bf16* wob    = (bf16*)alloc((size_t)CD * CD * 2);
  float* kraw  = (float*)alloc((size_t)BD * LD * CD * 4);
  float* vraw  = (float*)alloc((size_t)BD * LD * CD * 4);
  bf16* kh     = (bf16*)alloc((size_t)BD * NH_ * LD * HD_ * 2);
  bf16* vt     = (bf16*)alloc((size_t)BD * NH_ * HD_ * 96 * 2);
  float* qraw = out;  // d_out doubles as fp32 q scratch until the final GEMM
  bf16* qbf = xt;     // xt dead after Q-GEMM; reuse for normalized q

  // 0: convert inputs
  xpose_cvt<<<dim3(HWD / 64, CD / 64, BD), 256, 0, stream>>>(x, xt);
  const int nt_ = BD * LD * DD;
  cvt_bf16_k<<<(nt_ / 8 + 255) / 256, 256, 0, stream>>>(text, textb, nt_);
  cvt_bf16_k<<<(CD * CD / 8 + 255) / 256, 256, 0, stream>>>(wq, wqb, CD * CD);
  cvt_bf16_k<<<(CD * DD / 8 + 255) / 256, 256, 0, stream>>>(wk, wkb, CD * DD);
  cvt_bf16_k<<<(CD * DD / 8 + 255) / 256, 256, 0, stream>>>(wv, wvb, CD * DD);
  cvt_bf16_k<<<(CD * CD / 8 + 255) / 256, 256, 0, stream>>>(wo, wob, CD * CD);

  // 1: K/V projections (M=1232 padded to 10 tiles), LN(k), V transpose
  gemm_bt<128, 128, 1><<<dim3(4, 10), 256, 0, stream>>>(
      textb, wkb, BD * LD, CD, DD, bk, nullptr, kraw);
  gemm_bt<128, 128, 1><<<dim3(4, 10), 256, 0, stream>>>(
      textb, wvb, BD * LD, CD, DD, bv, nullptr, vraw);
  ln_rows<<<(BD * LD) / 4, 256, 0, stream>>>(kraw, g2, b2, kh, BD * LD, 1);
  make_vt<<<BD * NH_, 256, 0, stream>>>(vraw, vt);

  // 2: Q projection (+bias +posenc) then LN -> bf16
  gemm_bt<128, 256, 0><<<dim3(2, 512), 256, 0, stream>>>(
      xt, wqb, BD * HWD, CD, CD, bq, nullptr, qraw);
  ln_rows<<<(BD * HWD) / 4, 256, 0, stream>>>(qraw, g1, b1, qbf, BD * HWD, 0);

  // 3: attention
  attn_k<<<dim3(HWD / 64, NH_, BD), 256, 0, stream>>>(qbf, kh, vt, attn_o);

  // 4: output projection (+bias +residual), computed transposed for coalescing
  gemm_bt<256, 128, 3><<<dim3(512, 2), 256, 0, stream>>>(
      wob, attn_o, CD, BD * HWD, CD, bo, x, out);
}